// Round 4
// baseline (3246.561 us; speedup 1.0000x reference)
//
#include <hip/hip_runtime.h>
#include <stdint.h>

// Problem constants
#define BB   128      // batch
#define LL   128      // latent dim
#define HH   1024     // hidden
#define G4   4096     // 4*H
#define TT   256      // time steps
#define PP   128      // output cols per step

#define NGB  64                  // gate blocks: each owns 16 hidden units (64 weight rows)
#define NFB  8                   // fc blocks: each owns 16 rows of W_fc
#define NB   (NGB + NFB)

// HW_REG_XCC_ID = hwreg id 20, offset 0, size 32 -> imm = 20 | (0<<6) | (31<<11)
#define XCC_HWREG 63508

typedef _Float16 half8  __attribute__((ext_vector_type(8)));
typedef float   floatx4 __attribute__((ext_vector_type(4)));

__device__ __forceinline__ float sigf(float x) {
  x = fminf(fmaxf(x, -30.f), 30.f);
  return 1.f / (1.f + __expf(-x));
}
__device__ __forceinline__ float tanhf_fast(float x) {
  x = fminf(fmaxf(x, -15.f), 15.f);
  float e = __expf(2.f * x);
  return (e - 1.f) / (e + 1.f);
}
__device__ __forceinline__ unsigned short f2h(float x) {
  _Float16 h = (_Float16)x;
  return __builtin_bit_cast(unsigned short, h);
}
// system-scope write-through h store: visible at LLC once vmcnt(0) drains
__device__ __forceinline__ void store_h(unsigned short* p, float x) {
  __hip_atomic_store(p, f2h(x), __ATOMIC_RELAXED, __HIP_MEMORY_SCOPE_SYSTEM);
}
// system-scope 16B load: bypasses L1+L2, reads coherent LLC. NOT tracked by the
// compiler's waitcnt pass — pair every consumer with waitv2<K>() below.
__device__ __forceinline__ void load_sys(half8& d, const half8* p) {
  asm volatile("global_load_dwordx4 %0, %1, off sc0 sc1" : "=v"(d) : "v"(p));
}
// s_waitcnt vmcnt(K), register-tied to the two values being waited on so the
// compiler cannot move their consumers above the wait (or the loads below it).
template <int K>
__device__ __forceinline__ void waitv2(half8& a, half8& b) {
  asm volatile("s_waitcnt vmcnt(%2)" : "+v"(a), "+v"(b) : "n"(K));
}

// Flat monotonic grid barrier with full fences (startup only).
__device__ __forceinline__ void gridbar_flat(unsigned* bar, unsigned target) {
  __syncthreads();
  if (threadIdx.x == 0) {
    __threadfence();
    atomicAdd(bar, 1u);
    while (__hip_atomic_load(bar, __ATOMIC_RELAXED, __HIP_MEMORY_SCOPE_AGENT) < target)
      __builtin_amdgcn_s_sleep(1);
    __threadfence();
  }
  __syncthreads();
}

// Fence-free hierarchical per-step barrier: data visibility comes from
// system-scope write-through stores (drained by vmcnt(0)) + system-scope reads.
__device__ __forceinline__ void stepbar(unsigned* lbar, unsigned* gbar,
                                        unsigned lcnt, unsigned nldr, bool leader,
                                        unsigned s) {
  __syncthreads();
  if (threadIdx.x == 0) {
    asm volatile("s_waitcnt vmcnt(0)" ::: "memory");   // h stores ack'd at LLC
    __hip_atomic_fetch_add(lbar, 1u, __ATOMIC_RELAXED, __HIP_MEMORY_SCOPE_AGENT);
    if (leader) {
      while (__hip_atomic_load(lbar, __ATOMIC_RELAXED, __HIP_MEMORY_SCOPE_AGENT) < lcnt * s)
        __builtin_amdgcn_s_sleep(1);
      __hip_atomic_fetch_add(gbar, 1u, __ATOMIC_RELAXED, __HIP_MEMORY_SCOPE_AGENT);
    }
    while (__hip_atomic_load(gbar, __ATOMIC_RELAXED, __HIP_MEMORY_SCOPE_AGENT) < nldr * s)
      __builtin_amdgcn_s_sleep(1);
  }
  __syncthreads();
}

// gates0 = z @ w_ih^T + b_ih + b_hh   (step-0 gates; h0=c0=0, x=0 for t>=1)
__global__ void prep_gates0(const float* __restrict__ z, const float* __restrict__ w_ih,
                            const float* __restrict__ b_ih, const float* __restrict__ b_hh,
                            float* __restrict__ g0) {
  int j = blockIdx.x;     // 0..4095
  int b = threadIdx.x;    // 0..127
  const float* zr = z + b * LL;
  const float* wr = w_ih + (size_t)j * LL;
  float s = 0.f;
#pragma unroll 4
  for (int k = 0; k < LL; ++k) s += zr[k] * wr[k];
  g0[(size_t)b * G4 + j] = s + b_ih[j] + b_hh[j];
}

// Convert w_hh / W_fc to fp16 in the persistent kernel's LDS layout.
// Gate block bid owns units u = bid*16 .. bid*16+15; LDS rows (tile*16+nl) for
// tile 0..3 = gates i,g,f,o of unit nl. Each row's 8-elem k-chunks are
// XOR-swizzled by (nl&7) so the wave's B-reads are same-bank-free.
__global__ void prep_weights(const float* __restrict__ w_hh, const float* __restrict__ W_fc,
                             unsigned short* __restrict__ wbuf) {
  int R = blockIdx.x;                 // 0..4223 (4096 gate rows + 128 fc rows)
  const float* src; int rsw;
  if (R < NGB * 64) {
    int bid = R >> 6, rr = R & 63, tile = rr >> 4, nl = rr & 15;
    int g = (tile == 0) ? 0 : (tile == 1) ? 2 : (tile == 2) ? 1 : 3;  // i,g,f,o
    src = w_hh + (size_t)(g * HH + bid * 16 + nl) * HH;
    rsw = nl & 7;
  } else {
    int p = R - NGB * 64;
    src = W_fc + (size_t)p * HH;
    rsw = p & 7;
  }
  unsigned short* dst = wbuf + (size_t)R * HH;
  for (int k = threadIdx.x; k < HH; k += blockDim.x) {
    int dk = (((k >> 3) ^ rsw) << 3) | (k & 7);
    _Float16 v = (_Float16)src[k];
    dst[dk] = __builtin_bit_cast(unsigned short, v);
  }
}

// One k-chunk of the K=1024 MFMA pass (compile-time KC for the asm vmcnt imm).
// Pipeline: 16-deep x 2-stream prefetch (32 loads in flight); per chunk wait
// to vmcnt(30) [tail: 62-2*KC], consume, reissue.
template <int KC, int NT>
__device__ __forceinline__ void kstep(const half8* a0p, const half8* a1p,
                                      const half8* __restrict__ w8,
                                      half8 (&ap0)[16], half8 (&ap1)[16],
                                      int quad, int rsw, int l15,
                                      floatx4 acc[2][NT]) {
  constexpr int K = (KC < 16) ? 30 : (62 - 2 * KC);
  waitv2<K>(ap0[KC & 15], ap1[KC & 15]);
  half8 a0 = ap0[KC & 15], a1 = ap1[KC & 15];
  if constexpr (KC < 16) {
    load_sys(ap0[KC], a0p + (KC + 16) * 4);
    load_sys(ap1[KC], a1p + (KC + 16) * 4);
  }
  const int sw = (KC * 4 + quad) ^ rsw;
#pragma unroll
  for (int nt = 0; nt < NT; ++nt) {
    half8 b = w8[(nt * 16 + l15) * 128 + sw];
    acc[0][nt] = __builtin_amdgcn_mfma_f32_16x16x32_f16(a0, b, acc[0][nt], 0, 0, 0);
    acc[1][nt] = __builtin_amdgcn_mfma_f32_16x16x32_f16(a1, b, acc[1][nt], 0, 0, 0);
  }
}

template <int KC, int NT>
__device__ __forceinline__ void krun(const half8* a0p, const half8* a1p,
                                     const half8* __restrict__ w8,
                                     half8 (&ap0)[16], half8 (&ap1)[16],
                                     int quad, int rsw, int l15,
                                     floatx4 acc[2][NT]) {
  if constexpr (KC < 32) {
    kstep<KC, NT>(a0p, a1p, w8, ap0, ap1, quad, rsw, l15, acc);
    krun<KC + 1, NT>(a0p, a1p, w8, ap0, ap1, quad, rsw, l15, acc);
  }
}

template <int NT>
__device__ __forceinline__ void gemm2xNT(const half8* a0p, const half8* a1p,
                                         const half8* __restrict__ w8,
                                         int quad, int rsw, int l15,
                                         floatx4 acc[2][NT]) {
  half8 ap0[16], ap1[16];
#pragma unroll
  for (int i = 0; i < 16; ++i) {
    load_sys(ap0[i], a0p + i * 4);
    load_sys(ap1[i], a1p + i * 4);
  }
  krun<0, NT>(a0p, a1p, w8, ap0, ap1, quad, rsw, l15, acc);
}

__global__ __launch_bounds__(256, 1) void lstm_persist(
    const float* __restrict__ g0,
    const unsigned short* __restrict__ wbuf,
    const float* __restrict__ b_ih, const float* __restrict__ b_hh,
    const float* __restrict__ b_fc,
    float* __restrict__ out,
    unsigned short* __restrict__ hbuf,   // [2][B][H] fp16 double buffer
    unsigned* __restrict__ ctl) {        // census[8] | flat | gbar | lbar[8]
  extern __shared__ __align__(16) unsigned short sW[];
  const int tid  = threadIdx.x;
  const int wv   = tid >> 6;
  const int lane = tid & 63;
  const int quad = lane >> 4;
  const int l15  = lane & 15;
  const int bid  = blockIdx.x;
  const bool isg = bid < NGB;
  const int rsw  = l15 & 7;

  unsigned* census = ctl;            // 8 uints (one line)
  unsigned* fbar   = ctl + 32;       // flat barrier counter
  unsigned* gbar   = ctl + 64;       // global step counter
  // per-XCD lines at ctl + 128 + x*32 (128 B apart)

  // census: which physical XCD am I on, and am I its leader?
  unsigned myx = 0, rank = 0;
  if (tid == 0) {
    myx  = __builtin_amdgcn_s_getreg(XCC_HWREG) & 7u;
    rank = atomicAdd(&census[myx], 1u);
  }

  { // stage this block's weight slice into LDS (already fp16 + swizzled in wbuf)
    const uint4* s4 = (const uint4*)(wbuf +
        (size_t)(isg ? bid * 64 : NGB * 64 + (bid - NGB) * 16) * HH);
    uint4* d4 = (uint4*)sW;
    const int n16 = (isg ? 64 * HH : 16 * HH) / 8;
    for (int i = tid; i < n16; i += 256) d4[i] = s4[i];
  }
  __syncthreads();
  const half8* w8 = (const half8*)sW;
  const floatx4 z4 = {0.f, 0.f, 0.f, 0.f};

  if (isg) {
    const int u = bid * 16 + l15;   // hidden unit this lane owns (all 4 gates)
    const float bi = b_ih[u]          + b_hh[u];
    const float bf = b_ih[HH + u]     + b_hh[HH + u];
    const float bg = b_ih[2*HH + u]   + b_hh[2*HH + u];
    const float bo = b_ih[3*HH + u]   + b_hh[3*HH + u];
    float c[2][4] = {{0,0,0,0},{0,0,0,0}};

    // ---- t = 0: gates precomputed in g0; c_prev = 0
#pragma unroll
    for (int mt = 0; mt < 2; ++mt)
#pragma unroll
      for (int r = 0; r < 4; ++r) {
        const int m = wv * 32 + mt * 16 + quad * 4 + r;
        const float* gr = g0 + (size_t)m * G4;
        float iv = gr[u], gv = gr[2 * HH + u], ov = gr[3 * HH + u];
        float ct = sigf(iv) * tanhf_fast(gv);
        c[mt][r] = ct;
        store_h(hbuf + (size_t)m * HH + u, sigf(ov) * tanhf_fast(ct));
      }
    gridbar_flat(fbar, NB);   // also publishes census

    unsigned lcnt = 0, nldr = 0; unsigned* lbar = nullptr; bool leader = false;
    if (tid == 0) {
      lcnt = __hip_atomic_load(&census[myx], __ATOMIC_RELAXED, __HIP_MEMORY_SCOPE_AGENT);
      for (int i = 0; i < 8; ++i)
        nldr += (__hip_atomic_load(&census[i], __ATOMIC_RELAXED, __HIP_MEMORY_SCOPE_AGENT) > 0);
      lbar = ctl + 128 + myx * 32;
      leader = (rank == 0);
    }

    const int aoff0 = (wv * 32 +      l15) * 128 + quad;
    const int aoff1 = (wv * 32 + 16 + l15) * 128 + quad;

    for (int t = 1; t < TT; ++t) {
      const half8* hb8 = (const half8*)(hbuf + (size_t)((t - 1) & 1) * BB * HH);
      unsigned short* hw = hbuf + (size_t)(t & 1) * BB * HH;
      floatx4 acc[2][4] = {{z4, z4, z4, z4}, {z4, z4, z4, z4}};
      gemm2xNT<4>(hb8 + aoff0, hb8 + aoff1, w8, quad, rsw, l15, acc);
#pragma unroll
      for (int mt = 0; mt < 2; ++mt)
#pragma unroll
        for (int r = 0; r < 4; ++r) {
          float iv = sigf(acc[mt][0][r] + bi);
          float gv = tanhf_fast(acc[mt][1][r] + bg);
          float fv = sigf(acc[mt][2][r] + bf);
          float ov = sigf(acc[mt][3][r] + bo);
          float ct = fv * c[mt][r] + iv * gv;
          c[mt][r] = ct;
          const int m = wv * 32 + mt * 16 + quad * 4 + r;
          store_h(hw + (size_t)m * HH + u, ov * tanhf_fast(ct));
        }
      stepbar(lbar, gbar, lcnt, nldr, leader, (unsigned)t);
    }
  } else {
    // fc block: y_{t-1} = h_{t-1} @ W_fc^T + b_fc, overlapped with step-t gate GEMMs
    const int fb = bid - NGB;
    const int pcol = fb * 16 + l15;
    const float biasf = b_fc[pcol];
    const int aoff0 = ((wv * 2 + 0) * 16 + l15) * 128 + quad;
    const int aoff1 = ((wv * 2 + 1) * 16 + l15) * 128 + quad;

    gridbar_flat(fbar, NB);   // t = 0: nothing to project yet; also publishes census

    unsigned lcnt = 0, nldr = 0; unsigned* lbar = nullptr; bool leader = false;
    if (tid == 0) {
      lcnt = __hip_atomic_load(&census[myx], __ATOMIC_RELAXED, __HIP_MEMORY_SCOPE_AGENT);
      for (int i = 0; i < 8; ++i)
        nldr += (__hip_atomic_load(&census[i], __ATOMIC_RELAXED, __HIP_MEMORY_SCOPE_AGENT) > 0);
      lbar = ctl + 128 + myx * 32;
      leader = (rank == 0);
    }

    for (int t = 1; t <= TT; ++t) {
      const half8* hb8 = (const half8*)(hbuf + (size_t)((t - 1) & 1) * BB * HH);
      floatx4 acc[2][1] = {{z4}, {z4}};
      gemm2xNT<1>(hb8 + aoff0, hb8 + aoff1, w8, quad, rsw, l15, acc);
#pragma unroll
      for (int mt = 0; mt < 2; ++mt)
#pragma unroll
        for (int r = 0; r < 4; ++r) {
          const int m = (wv * 2 + mt) * 16 + quad * 4 + r;
          out[(size_t)m * (TT * PP) + (size_t)(t - 1) * PP + pcol] = acc[mt][0][r] + biasf;
        }
      if (t < TT) stepbar(lbar, gbar, lcnt, nldr, leader, (unsigned)t);
    }
  }
}

extern "C" void kernel_launch(void* const* d_in, const int* in_sizes, int n_in,
                              void* d_out, int out_size, void* d_ws, size_t ws_size,
                              hipStream_t stream) {
  const float* z    = (const float*)d_in[1];
  const float* w_ih = (const float*)d_in[2];
  const float* w_hh = (const float*)d_in[3];
  const float* b_ih = (const float*)d_in[4];
  const float* b_hh = (const float*)d_in[5];
  const float* W_fc = (const float*)d_in[6];
  const float* b_fc = (const float*)d_in[7];
  float* out = (float*)d_out;

  // workspace layout (~10.8 MiB total)
  char* ws = (char*)d_ws;
  unsigned*       ctl  = (unsigned*)ws;                                        // 4 KiB ctrl
  unsigned short* hbuf = (unsigned short*)(ws + 4096);                         // 512 KiB
  float*          g0   = (float*)(ws + 4096 + (size_t)2 * BB * HH * 2);        // 2 MiB
  unsigned short* wbuf = (unsigned short*)(ws + 4096 + (size_t)2 * BB * HH * 2
                                              + (size_t)BB * G4 * 4);          // 8.25 MiB

  // allow 128 KiB dynamic LDS (gfx950 has 160 KiB/CU)
  (void)hipFuncSetAttribute(reinterpret_cast<const void*>(lstm_persist),
                            hipFuncAttributeMaxDynamicSharedMemorySize, 160 * 1024);

  hipMemsetAsync(ctl, 0, 4096, stream);
  prep_gates0 <<<dim3(G4), dim3(BB), 0, stream>>>(z, w_ih, b_ih, b_hh, g0);
  prep_weights<<<dim3(NGB * 64 + NFB * 16), dim3(256), 0, stream>>>(w_hh, W_fc, wbuf);
  lstm_persist<<<dim3(NB), dim3(256), 128 * 1024, stream>>>(g0, wbuf, b_ih, b_hh, b_fc,
                                                            out, hbuf, ctl);
}